// Round 1
// baseline (526.668 us; speedup 1.0000x reference)
//
#include <hip/hip_runtime.h>
#include <hip/hip_bf16.h>

// ModulatedConv2d: B=16, Cin=Cout=512, H=W=64, 3x3, pad 1.
// out[b,o] = dscale[b,o] * conv2d(s[b,:]*x[b], weight)   (weights shared across batch)

constexpr float CONV_SCALE = 0.014731391274719738f;  // 1/sqrt(512*9)
constexpr float MOD_SCALE  = 0.04419417382415922f;   // 1/sqrt(512)

typedef short  bf16x8 __attribute__((ext_vector_type(8)));
typedef float  f32x4  __attribute__((ext_vector_type(4)));

__device__ __forceinline__ unsigned short f2bf(float f) {
  unsigned u = __float_as_uint(f);
  u += 0x7fffu + ((u >> 16) & 1u);           // round-to-nearest-even
  return (unsigned short)(u >> 16);
}

__device__ __forceinline__ void async16(const void* g, void* l) {
  __builtin_amdgcn_global_load_lds((const __attribute__((address_space(1))) unsigned int*)g,
                                   (__attribute__((address_space(3))) unsigned int*)l,
                                   16, 0, 0);
}

// ---------- kernel 1: s[b,i] = style[b,:] . mod_weight[i,:] * MOD_SCALE + mod_bias[i] ----------
__global__ void k_style(const float* __restrict__ style, const float* __restrict__ mw,
                        const float* __restrict__ mb, float* __restrict__ s) {
  int t = blockIdx.x * 256 + threadIdx.x;    // 8192 threads
  int b = t & 15, i = t >> 4;
  const float4* st = (const float4*)(style + b * 512);
  const float4* wr = (const float4*)(mw + i * 512);
  float acc = 0.f;
#pragma unroll 8
  for (int j = 0; j < 128; ++j) {
    float4 a = st[j], w4 = wr[j];
    acc += a.x * w4.x + a.y * w4.y + a.z * w4.z + a.w * w4.w;
  }
  s[b * 512 + i] = acc * MOD_SCALE + mb[i];
}

// ---------- kernel 2: wsq[o,i] = sum_taps w^2 ; wt[kh][kw][o][ic] = bf16(w) ----------
__global__ void k_prepw(const float* __restrict__ w, float* __restrict__ wsq,
                        unsigned short* __restrict__ wt) {
  __shared__ float Wl[2304];
  int t = threadIdx.x;
  size_t base = (size_t)blockIdx.x * 2304;
#pragma unroll
  for (int k = 0; k < 3; ++k) {
    int idx = t + k * 256;
    if (idx < 576) ((float4*)Wl)[idx] = ((const float4*)(w + base))[idx];
  }
  __syncthreads();
  int g = blockIdx.x * 256 + t;
  int ic = g & 511, o = g >> 9;
  float ssq = 0.f;
#pragma unroll
  for (int tap = 0; tap < 9; ++tap) {
    float v = Wl[t * 9 + tap];
    ssq += v * v;
    wt[((size_t)tap * 512 + o) * 512 + ic] = f2bf(v);
  }
  wsq[o * 512 + ic] = ssq;
}

// ---------- kernel 3: dscale[b,o] = rsqrt(CS^2 * sum_i wsq[o,i]*s[b,i]^2 + 1e-8) * CS ----------
__global__ void k_dscale(const float* __restrict__ s, const float* __restrict__ wsq,
                         float* __restrict__ dscale) {
  int t = blockIdx.x * 256 + threadIdx.x;    // 8192 threads
  int b = t & 15, o = t >> 4;
  const float4* sq = (const float4*)(wsq + o * 512);
  const float4* sb = (const float4*)(s + b * 512);
  float acc = 0.f;
#pragma unroll 8
  for (int j = 0; j < 128; ++j) {
    float4 q4 = sq[j], s4 = sb[j];
    acc += q4.x * s4.x * s4.x + q4.y * s4.y * s4.y + q4.z * s4.z * s4.z + q4.w * s4.w * s4.w;
  }
  float d = rsqrtf(CONV_SCALE * CONV_SCALE * acc + 1e-8f);
  dscale[b * 512 + o] = d * CONV_SCALE;
}

// ---------- kernel 3b: zero the two padded halo rows (hp=0 and hp=65) of xt for each b ----------
// xt layout: [b][hp=66][w=64][ic=512] bf16.  Padded rows make every k_conv staging load valid,
// keeping per-wave vmcnt counts uniform (required for the counted-waitcnt pipeline).
__global__ void k_zpad(unsigned short* __restrict__ xt) {
  int strip = blockIdx.x;                    // 32 strips: 16 b x {row 0, row 65}
  int b = strip >> 1, sel = strip & 1;
  unsigned short* p = xt + ((size_t)(b * 66 + sel * 65) * 64) * 512;
  int4 z = {0, 0, 0, 0};
  for (int idx = threadIdx.x; idx < 4096; idx += 256)   // 64*512 bf16 = 65536 B
    ((int4*)p)[idx] = z;
}

// ---------- kernel 4: xt[b][h+1][w][ic] = bf16(x[b][ic][h][w] * s[b][ic])  (NCHW->NHWC) ----------
// LDS transpose with float4-group XOR swizzle: group g of row r stored at g ^ (r>>3).
// Kills the previous 8-way bank conflict on the column gather (now 2 lanes/bank = free).
__global__ void k_xt(const float* __restrict__ x, const float* __restrict__ s,
                     unsigned short* __restrict__ xt) {
  __shared__ float T[64][68];
  int h = blockIdx.x, b = blockIdx.y;
  const float* xp = x + (size_t)b * 512 * 4096 + h * 64;
  unsigned short* xo = xt + ((size_t)((b * 66) + h + 1) * 64) * 512;
  int t = threadIdx.x;
  for (int ic0 = 0; ic0 < 512; ic0 += 64) {
    // load 64 ic-rows x 64 w as float4 (coalesced 16B/lane), scale by s, swizzled store
#pragma unroll
    for (int k = 0; k < 4; ++k) {
      int idx = t + k * 256;          // 1024 float4s
      int icl = idx >> 4, c4 = idx & 15;
      int ic = ic0 + icl;
      float4 v = *(const float4*)&xp[(size_t)ic * 4096 + c4 * 4];
      float sc = s[b * 512 + ic];
      v.x *= sc; v.y *= sc; v.z *= sc; v.w *= sc;
      *(float4*)&T[icl][(c4 ^ (icl >> 3)) << 2] = v;
    }
    __syncthreads();
    // transpose out: [w][ic] with 8-ch bf16 packs; conflict-free column reads via the swizzle
#pragma unroll
    for (int c = t; c < 512; c += 256) {   // 64 w * 8 groups of 8 ch
      int wv = c >> 3, ig = (c & 7) * 8;
      // rows ig..ig+7 share (row>>3) == (c&7); element wv lives at swizzled float col:
      int colf = ((((c >> 3) >> 2) ^ (c & 7)) << 2) + ((c >> 3) & 3);
      unsigned p0 = (unsigned)f2bf(T[ig + 0][colf]) | ((unsigned)f2bf(T[ig + 1][colf]) << 16);
      unsigned p1 = (unsigned)f2bf(T[ig + 2][colf]) | ((unsigned)f2bf(T[ig + 3][colf]) << 16);
      unsigned p2 = (unsigned)f2bf(T[ig + 4][colf]) | ((unsigned)f2bf(T[ig + 5][colf]) << 16);
      unsigned p3 = (unsigned)f2bf(T[ig + 6][colf]) | ((unsigned)f2bf(T[ig + 7][colf]) << 16);
      uint4 pk = {p0, p1, p2, p3};
      *(uint4*)&xo[(size_t)wv * 512 + ic0 + ig] = pk;
    }
    __syncthreads();
  }
}

// ---------- kernel 5: the conv (implicit GEMM, MFMA bf16, counted-vmcnt pipeline) ----------
// grid (8 h-tiles, 4 o-tiles, 16 b); block 512 = 8 waves.  Tile: 128 o x (8 rows x 64 cols).
// Wave: 128 o x 1 row; 8x4 accs of 16x16.  X and W double-buffered; 3 phases per ic0 step
// (kh=0,1,2); per phase: issue next stage -> s_waitcnt vmcnt(N) -> s_barrier -> MFMA -> s_barrier.
// vmcnt FIFO (per wave, 3 W loads/stage, 5 X loads/stage):
//   (i,A): issue W(i,1)+X(i+1): queue [W(i,0)3 | W(i,1)3 X(i+1)5] -> need W(i,0)   -> vmcnt(8)
//   (i,B): issue W(i,2):        queue [W(i,1)3 | X(i+1)5 W(i,2)3] -> need W(i,1)   -> vmcnt(8)
//   (i,C): issue W(i+1,0):      queue [X(i+1)5 W(i,2)3 | W(i+1,0)3] -> need W(i,2) -> vmcnt(3)
// LDS images chunk-swizzled (16B chunk q of 64B row r lives at q ^ ((r>>1)&3)); achieved by
// XOR-ing the per-lane GLOBAL source address (linear global_load_lds dest, rule 21) and the
// same XOR on the ds_read side -> each 8-consecutive-lane group hits all 8 16B slots.
__global__ __launch_bounds__(512, 2)
void k_conv(const unsigned short* __restrict__ xt, const unsigned short* __restrict__ wt,
            const float* __restrict__ dscale, float* __restrict__ out) {
  __shared__ short Xs[2][10 * 66 * 32];   // 2 x 41.25 KB: [row(8+2 halo)][col(pad+64+pad)][ic32]
  __shared__ short Ws[2][3 * 128 * 32];   // 2 x 24 KB:    [kw][o128][ic32]

  const int b  = blockIdx.z;
  const int o0 = blockIdx.y * 128;
  const int h0 = blockIdx.x * 8;
  const int t = threadIdx.x;
  const int wave = t >> 6, lane = t & 63;
  const int q = lane >> 4, l16 = lane & 15;

  // staging-source swizzle offsets (shorts).  X cols sit at LDS col 1+lc -> s=(((lc)+1)>>1)&3.
  const int xsrc8 = ((lane & 3) ^ ((((lane >> 2) + 1) >> 1) & 3)) * 8;
  const int wsrc8 = ((lane & 3) ^ ((lane >> 3) & 3)) * 8;
  // W-read swizzle: o-row = mi*16 + l16 -> s = (l16>>1)&3 (loop-invariant)
  const int wq8 = (q ^ ((l16 >> 1) & 3)) * 8;

  f32x4 acc[8][4];
#pragma unroll
  for (int i = 0; i < 8; ++i)
#pragma unroll
    for (int j = 0; j < 4; ++j) acc[i][j] = (f32x4){0.f, 0.f, 0.f, 0.f};

  // zero halo columns (col 0 and 65) of all 10 rows, BOTH buffers (full 64B col-rows: swizzle-inv.)
  for (int z = t; z < 640; z += 512) {
    int bi = (z >= 320) ? 1 : 0;
    int zz = z - bi * 320;
    int r = zz >> 5, rem = zz & 31;
    int col = (rem >> 4) * 65, ch2 = (rem & 15) * 2;
    *(int*)&Xs[bi][(r * 66 + col) * 32 + ch2] = 0;
  }

  auto stageX = [&](int i_, int xb_) {
    int ic0_ = i_ * 32;
#pragma unroll
    for (int j = 0; j < 5; ++j) {
      int c = wave * 5 + j;               // 40 chunks: 10 rows x 4 col-quarters
      int row = c >> 2, q16 = c & 3;
      async16(xt + ((size_t)((b * 66 + h0 + row) * 64) + q16 * 16 + (lane >> 2)) * 512 + ic0_ + xsrc8,
              &Xs[xb_][(row * 66 + 1 + q16 * 16) * 32]);
    }
  };
  auto stageW = [&](int i_, int kh_, int wb_) {
    int ic0_ = i_ * 32;
#pragma unroll
    for (int j = 0; j < 3; ++j) {
      int ci = wave * 3 + j;              // 24 chunks: 3 kw x 8 o-groups
      int kw = ci >> 3, oo = ((ci & 7) << 4) + (lane >> 2);
      async16(wt + (((size_t)(kh_ * 3 + kw) * 512 + o0 + oo) * 512 + ic0_ + wsrc8),
              &Ws[wb_][ci * 512]);
    }
  };
  auto compute = [&](int kh, int xb_, int wb_) {
    const short* Xrow = &Xs[xb_][(wave + kh) * 66 * 32];
    const short* Wb = Ws[wb_];
    __builtin_amdgcn_s_setprio(1);
#pragma unroll
    for (int kw = 0; kw < 3; ++kw) {
      bf16x8 bfr[4];
#pragma unroll
      for (int ni = 0; ni < 4; ++ni) {
        int c = ni * 16 + l16 + kw;
        bfr[ni] = *(const bf16x8*)&Xrow[c * 32 + ((q ^ ((c >> 1) & 3)) << 3)];
      }
#pragma unroll
      for (int mi = 0; mi < 8; ++mi) {
        bf16x8 af = *(const bf16x8*)&Wb[(kw * 128 + mi * 16 + l16) * 32 + wq8];
#pragma unroll
        for (int ni = 0; ni < 4; ++ni)
          acc[mi][ni] = __builtin_amdgcn_mfma_f32_16x16x32_bf16(af, bfr[ni], acc[mi][ni], 0, 0, 0);
      }
    }
    __builtin_amdgcn_s_setprio(0);
  };

  // prologue: stage ic0=0 (X and W(0,0)) into buffer 0; full drain once.
  stageX(0, 0);
  stageW(0, 0, 0);
  __syncthreads();

#pragma unroll 2
  for (int i = 0; i < 16; ++i) {
    const int xb = i & 1;
    const int inext = (i < 15) ? i + 1 : 15;   // tail: dummy re-stage into the unread buffer
    // ---- phase A (kh=0): reads Xs[xb], Ws[xb]
    stageW(i, 1, xb ^ 1);
    stageX(inext, xb ^ 1);
    asm volatile("s_waitcnt vmcnt(8)" ::: "memory");
    __builtin_amdgcn_s_barrier();
    __builtin_amdgcn_sched_barrier(0);
    compute(0, xb, xb);
    __builtin_amdgcn_sched_barrier(0);
    __builtin_amdgcn_s_barrier();
    // ---- phase B (kh=1): reads Ws[xb^1]
    stageW(i, 2, xb);
    asm volatile("s_waitcnt vmcnt(8)" ::: "memory");
    __builtin_amdgcn_s_barrier();
    __builtin_amdgcn_sched_barrier(0);
    compute(1, xb, xb ^ 1);
    __builtin_amdgcn_sched_barrier(0);
    __builtin_amdgcn_s_barrier();
    // ---- phase C (kh=2): reads Ws[xb]
    stageW(inext, 0, xb ^ 1);
    asm volatile("s_waitcnt vmcnt(3)" ::: "memory");
    __builtin_amdgcn_s_barrier();
    __builtin_amdgcn_sched_barrier(0);
    compute(2, xb, xb);
    __builtin_amdgcn_sched_barrier(0);
    __builtin_amdgcn_s_barrier();
  }
  asm volatile("s_waitcnt vmcnt(0)" ::: "memory");   // drain tail dummy stages before exit path

  // ---- epilogue: D[row=q*4+r][col=l16] per 16x16 frag; scale by dscale[b,o]
  const int h = h0 + wave;
#pragma unroll
  for (int mi = 0; mi < 8; ++mi) {
#pragma unroll
    for (int r = 0; r < 4; ++r) {
      int o_l = mi * 16 + q * 4 + r;
      float ds = dscale[b * 512 + o0 + o_l];
      float* orow = out + ((size_t)(b * 512 + o0 + o_l) * 64 + h) * 64;
#pragma unroll
      for (int ni = 0; ni < 4; ++ni)
        orow[ni * 16 + l16] = acc[mi][ni][r] * ds;
    }
  }
}

extern "C" void kernel_launch(void* const* d_in, const int* in_sizes, int n_in,
                              void* d_out, int out_size, void* d_ws, size_t ws_size,
                              hipStream_t stream) {
  const float* x      = (const float*)d_in[0];  // (16,512,64,64)
  const float* style  = (const float*)d_in[1];  // (16,512)
  const float* weight = (const float*)d_in[2];  // (1,512,512,3,3)
  const float* mw     = (const float*)d_in[3];  // (512,512)
  const float* mb     = (const float*)d_in[4];  // (512,)
  float* out = (float*)d_out;

  // workspace layout
  float* s      = (float*)d_ws;                       // 8192 f32
  float* dscale = s + 8192;                           // 8192 f32
  float* wsq    = dscale + 8192;                      // 262144 f32
  unsigned short* wt = (unsigned short*)(wsq + 262144);  // 9*512*512 bf16 = 4.5 MiB
  unsigned short* xt = wt + 9 * 512 * 512;            // 16*66*64*512 bf16 = 66 MiB (2 halo rows/b)

  k_style<<<32, 256, 0, stream>>>(style, mw, mb, s);
  k_prepw<<<1024, 256, 0, stream>>>(weight, wsq, wt);
  k_dscale<<<32, 256, 0, stream>>>(s, wsq, dscale);
  k_zpad<<<32, 256, 0, stream>>>(xt);
  k_xt<<<dim3(64, 16), 256, 0, stream>>>(x, s, xt);
  k_conv<<<dim3(8, 4, 16), 512, 0, stream>>>(xt, wt, dscale, out);
}